// Round 1
// baseline (1318.312 us; speedup 1.0000x reference)
//
#include <hip/hip_runtime.h>
#include <math.h>

#define D_MODEL 1024
#define N_HEADS 16
#define HEAD_DIM 64
#define BATCH 2
#define SEQ 2048
#define NTOK (BATCH * SEQ)   // 4096

// ---------------------------------------------------------------------------
// RoPE cos/sin tables: ct/st[s*64 + d], angle = fp32(s * inv_freq[d&31]),
// trig in double of the fp32-rounded angle (mimics jnp fp32 rounding of freqs).
// ---------------------------------------------------------------------------
__global__ void rope_tables(float* __restrict__ ct, float* __restrict__ st) {
    int s = blockIdx.x;        // 0..2047
    int d = threadIdx.x;       // 0..63
    int e = d & 31;
    float invf = 1.0f / powf(10000.0f, (float)e / 32.0f);
    float ang  = (float)s * invf;        // fp32 rounding as in reference
    double a   = (double)ang;
    ct[s * 64 + d] = (float)cos(a);
    st[s * 64 + d] = (float)sin(a);
}

// ---------------------------------------------------------------------------
// C[M,N] = X[M,K] @ W[N,K]^T   (M=4096, N=1024, K=1024, all row-major fp32)
// 64x64 tile / block of 256 threads, 4x4 microtile, BK=32 staged in LDS.
// ---------------------------------------------------------------------------
__global__ __launch_bounds__(256) void gemm_xwt(const float* __restrict__ X,
                                                const float* __restrict__ W,
                                                float* __restrict__ C) {
    __shared__ float As[32][68];   // [k][m], pad 68 keeps float4 alignment
    __shared__ float Bs[32][68];   // [k][n]

    const int bm  = blockIdx.y * 64;
    const int bn  = blockIdx.x * 64;
    const int tid = threadIdx.x;
    const int ty  = tid >> 4;      // 0..15 -> rows
    const int tx  = tid & 15;      // 0..15 -> cols
    const int ty4 = ty * 4, tx4 = tx * 4;

    float acc[4][4] = {};

    for (int k0 = 0; k0 < 1024; k0 += 32) {
        #pragma unroll
        for (int i = 0; i < 8; ++i) {
            int idx = i * 256 + tid;          // 0..2047
            int r   = idx >> 5;               // 0..63
            int kk  = idx & 31;               // 0..31 (fast -> coalesced)
            As[kk][r] = X[(bm + r) * 1024 + k0 + kk];
            Bs[kk][r] = W[(bn + r) * 1024 + k0 + kk];
        }
        __syncthreads();

        #pragma unroll 8
        for (int kk = 0; kk < 32; ++kk) {
            const float4 a = *(const float4*)&As[kk][ty4];
            const float4 b = *(const float4*)&Bs[kk][tx4];
            const float av[4] = {a.x, a.y, a.z, a.w};
            const float bv[4] = {b.x, b.y, b.z, b.w};
            #pragma unroll
            for (int i = 0; i < 4; ++i)
                #pragma unroll
                for (int j = 0; j < 4; ++j)
                    acc[i][j] = fmaf(av[i], bv[j], acc[i][j]);
        }
        __syncthreads();
    }

    #pragma unroll
    for (int i = 0; i < 4; ++i) {
        float4 o = {acc[i][0], acc[i][1], acc[i][2], acc[i][3]};
        *(float4*)&C[(bm + ty4 + i) * 1024 + bn + tx4] = o;
    }
}

// ---------------------------------------------------------------------------
// In-place RoPE on Q and K buffers [4096, 1024] (col j = h*64 + d).
// rotate_half convention: pair (d, d+32) within each 64-wide head.
// ---------------------------------------------------------------------------
__global__ void rope_apply(float* Q, float* K,
                           const float* __restrict__ ct,
                           const float* __restrict__ st) {
    int idx = blockIdx.x * blockDim.x + threadIdx.x;  // 0 .. 4096*16*32-1
    float* P = blockIdx.y ? K : Q;
    int d   = idx & 31;
    int h   = (idx >> 5) & 15;
    int tok = idx >> 9;
    int s   = tok & (SEQ - 1);
    int base = tok * 1024 + h * 64;
    float x0 = P[base + d];
    float x1 = P[base + d + 32];
    float c  = ct[s * 64 + d];
    float sn = st[s * 64 + d];
    P[base + d]      = x0 * c - x1 * sn;
    P[base + d + 32] = x1 * c + x0 * sn;   // cos/sin identical for d and d+32
}

// ---------------------------------------------------------------------------
// Flash attention fp32: one block per (q-tile 64, head, batch).
// Online softmax; KPs buffer is reused: K-tile (transposed) then P-tile.
// ---------------------------------------------------------------------------
__global__ __launch_bounds__(256) void flash_attn(const float* Qp,
                                                  const float* __restrict__ Kp,
                                                  const float* __restrict__ Vp,
                                                  float* Op) {
    __shared__ float Qs[64][68];    // [d][q]  (transposed)
    __shared__ float KPs[64][68];   // phase 1: K as [d][k]; phase 2: P as [k][q]
    __shared__ float Vs[64][68];    // [k][d]

    const int qt = blockIdx.x, h = blockIdx.y, b = blockIdx.z;
    const int tid = threadIdx.x;
    const int ty = tid >> 4, tx = tid & 15;
    const int ty4 = ty * 4, tx4 = tx * 4;
    const int tokq0   = b * SEQ + qt * 64;
    const int colbase = h * 64;

    // load Q tile transposed: Qs[d][q]
    #pragma unroll
    for (int i = 0; i < 16; ++i) {
        int idx = i * 256 + tid;
        int r = idx >> 6, d = idx & 63;
        Qs[d][r] = Qp[(tokq0 + r) * 1024 + colbase + d];
    }

    float m_i[4], l_i[4], oacc[4][4] = {};
    #pragma unroll
    for (int i = 0; i < 4; ++i) { m_i[i] = -1e30f; l_i[i] = 0.0f; }

    for (int kt = 0; kt < SEQ / 64; ++kt) {
        const int tokk0 = b * SEQ + kt * 64;
        __syncthreads();   // prev PV reads done (and Q-tile writes on iter 0)

        #pragma unroll
        for (int i = 0; i < 16; ++i) {
            int idx = i * 256 + tid;
            int r = idx >> 6, d = idx & 63;
            KPs[d][r] = Kp[(tokk0 + r) * 1024 + colbase + d];  // K transposed
            Vs[r][d]  = Vp[(tokk0 + r) * 1024 + colbase + d];  // V natural
        }
        __syncthreads();

        // scores: sc[i][j] = sum_d Q[q,d] * K[k,d], q=ty4+i, k=tx4+j
        float sc[4][4] = {};
        #pragma unroll 8
        for (int d = 0; d < 64; ++d) {
            const float4 a = *(const float4*)&Qs[d][ty4];
            const float4 kb = *(const float4*)&KPs[d][tx4];
            const float av[4] = {a.x, a.y, a.z, a.w};
            const float kv[4] = {kb.x, kb.y, kb.z, kb.w};
            #pragma unroll
            for (int i = 0; i < 4; ++i)
                #pragma unroll
                for (int j = 0; j < 4; ++j)
                    sc[i][j] = fmaf(av[i], kv[j], sc[i][j]);
        }
        #pragma unroll
        for (int i = 0; i < 4; ++i)
            #pragma unroll
            for (int j = 0; j < 4; ++j)
                sc[i][j] *= 0.125f;   // 1/sqrt(64)

        // online softmax (row stats replicated across the 16 tx lanes)
        #pragma unroll
        for (int i = 0; i < 4; ++i) {
            float mx = fmaxf(fmaxf(sc[i][0], sc[i][1]), fmaxf(sc[i][2], sc[i][3]));
            #pragma unroll
            for (int off = 1; off < 16; off <<= 1)
                mx = fmaxf(mx, __shfl_xor(mx, off));
            float m_new = fmaxf(m_i[i], mx);
            float alpha = __expf(m_i[i] - m_new);
            float rsum = 0.0f;
            #pragma unroll
            for (int j = 0; j < 4; ++j) {
                float p = __expf(sc[i][j] - m_new);
                sc[i][j] = p;
                rsum += p;
            }
            #pragma unroll
            for (int off = 1; off < 16; off <<= 1)
                rsum += __shfl_xor(rsum, off);
            l_i[i] = l_i[i] * alpha + rsum;
            m_i[i] = m_new;
            #pragma unroll
            for (int j = 0; j < 4; ++j) oacc[i][j] *= alpha;
        }

        __syncthreads();   // everyone done reading KPs as K

        // write P transposed into KPs: P[k][q]
        #pragma unroll
        for (int i = 0; i < 4; ++i)
            #pragma unroll
            for (int j = 0; j < 4; ++j)
                KPs[tx4 + j][ty4 + i] = sc[i][j];
        __syncthreads();

        // PV: oacc[i][j] += sum_k P[q,k] * V[k,d], d=tx4+j
        #pragma unroll 8
        for (int kk = 0; kk < 64; ++kk) {
            const float4 pa = *(const float4*)&KPs[kk][ty4];
            const float4 vb = *(const float4*)&Vs[kk][tx4];
            const float pv[4] = {pa.x, pa.y, pa.z, pa.w};
            const float vv[4] = {vb.x, vb.y, vb.z, vb.w};
            #pragma unroll
            for (int i = 0; i < 4; ++i)
                #pragma unroll
                for (int j = 0; j < 4; ++j)
                    oacc[i][j] = fmaf(pv[i], vv[j], oacc[i][j]);
        }
    }

    #pragma unroll
    for (int i = 0; i < 4; ++i) {
        float inv = 1.0f / l_i[i];
        float4 o = {oacc[i][0] * inv, oacc[i][1] * inv,
                    oacc[i][2] * inv, oacc[i][3] * inv};
        *(float4*)&Op[(tokq0 + ty4 + i) * 1024 + colbase + tx4] = o;
    }
}

// ---------------------------------------------------------------------------
extern "C" void kernel_launch(void* const* d_in, const int* in_sizes, int n_in,
                              void* d_out, int out_size, void* d_ws, size_t ws_size,
                              hipStream_t stream) {
    const float* hs = (const float*)d_in[0];
    const float* wq = (const float*)d_in[1];
    const float* wk = (const float*)d_in[2];
    const float* wv = (const float*)d_in[3];
    const float* wo = (const float*)d_in[4];
    float* out = (float*)d_out;

    float* Q  = (float*)d_ws;            // 4096*1024 fp32; attn out aliases Q
    float* K  = Q + (size_t)NTOK * 1024;
    float* V  = K + (size_t)NTOK * 1024;
    float* ct = V + (size_t)NTOK * 1024; // 2048*64
    float* st = ct + SEQ * 64;

    rope_tables<<<dim3(SEQ), dim3(64), 0, stream>>>(ct, st);

    dim3 ggrid(1024 / 64, NTOK / 64);    // (16, 64)
    gemm_xwt<<<ggrid, 256, 0, stream>>>(hs, wq, Q);
    gemm_xwt<<<ggrid, 256, 0, stream>>>(hs, wk, K);
    gemm_xwt<<<ggrid, 256, 0, stream>>>(hs, wv, V);

    rope_apply<<<dim3(NTOK * N_HEADS * 32 / 256, 2), 256, 0, stream>>>(Q, K, ct, st);

    flash_attn<<<dim3(SEQ / 64, N_HEADS, BATCH), 256, 0, stream>>>(Q, K, V, Q);

    gemm_xwt<<<ggrid, 256, 0, stream>>>(Q, wo, out);
}

// Round 2
// 229.085 us; speedup vs baseline: 5.7547x; 5.7547x over previous
//
#include <hip/hip_runtime.h>
#include <math.h>

#define SEQ 2048
#define NTOK 4096
#define DM 1024

typedef __bf16 bf16x8 __attribute__((ext_vector_type(8)));
typedef float  f32x4  __attribute__((ext_vector_type(4)));

__device__ __forceinline__ void gll16(const void* g, void* l) {
    __builtin_amdgcn_global_load_lds(
        (const __attribute__((address_space(1))) void*)g,
        (__attribute__((address_space(3))) void*)l, 16, 0, 0);
}

__device__ __forceinline__ f32x4 mfma16(bf16x8 a, bf16x8 b, f32x4 c) {
    return __builtin_amdgcn_mfma_f32_16x16x32_bf16(a, b, c, 0, 0, 0);
}

// ---------------------------------------------------------------------------
__global__ void rope_tables(float* __restrict__ ct, float* __restrict__ st) {
    int s = blockIdx.x;
    int d = threadIdx.x;           // 0..63
    int e = d & 31;
    float invf = 1.0f / powf(10000.0f, (float)e / 32.0f);
    float ang  = (float)s * invf;
    double a   = (double)ang;
    ct[s * 64 + d] = (float)cos(a);
    st[s * 64 + d] = (float)sin(a);
}

// ---------------------------------------------------------------------------
__global__ void f2bf(const float* __restrict__ src, __bf16* __restrict__ dst, int n4) {
    int i = blockIdx.x * 256 + threadIdx.x;
    if (i >= n4) return;
    float4 v = ((const float4*)src)[i];
    __bf16* o = dst + (long)i * 4;
    o[0] = (__bf16)v.x; o[1] = (__bf16)v.y; o[2] = (__bf16)v.z; o[3] = (__bf16)v.w;
}

// ---------------------------------------------------------------------------
__global__ void rope_apply_bf16(__bf16* Q, __bf16* K,
                                const float* __restrict__ ct,
                                const float* __restrict__ st) {
    int idx = blockIdx.x * 256 + threadIdx.x;
    __bf16* P = blockIdx.y ? K : Q;
    int d   = idx & 31;
    int hh  = (idx >> 5) & 15;
    int tok = idx >> 9;
    int s   = tok & (SEQ - 1);
    long base = (long)tok * DM + hh * 64;
    float x0 = (float)P[base + d];
    float x1 = (float)P[base + d + 32];
    float c  = ct[s * 64 + d];
    float sn = st[s * 64 + d];
    P[base + d]      = (__bf16)(x0 * c - x1 * sn);
    P[base + d + 32] = (__bf16)(x1 * c + x0 * sn);
}

// ---------------------------------------------------------------------------
template <typename OutT>
__global__ __launch_bounds__(256) void gemm_bf16(const __bf16* __restrict__ A,
                                                 const __bf16* __restrict__ B,
                                                 OutT* __restrict__ C,
                                                 int N) {
    __shared__ __bf16 As[128 * 64];
    __shared__ __bf16 Bs[128 * 64];
    const int tid  = threadIdx.x;
    const int lane = tid & 63;
    const int wid  = tid >> 6;
    const int l15  = lane & 15, lg = lane >> 4;
    const long bm = (long)blockIdx.y * 128, bn = (long)blockIdx.x * 128;
    const int wr = (wid >> 1) * 64, wc = (wid & 1) * 64;

    f32x4 acc[4][4];
    #pragma unroll
    for (int i = 0; i < 4; ++i)
        #pragma unroll
        for (int j = 0; j < 4; ++j) acc[i][j] = 0;

    const int srow = tid >> 3;
    const int sgz  = (tid & 7) ^ (srow & 7);
    const __bf16* Ag = A + (bm + srow) * 1024 + sgz * 8;
    const __bf16* Bg = B + (bn + srow) * 1024 + sgz * 8;

    for (int k0 = 0; k0 < 1024; k0 += 64) {
        __syncthreads();
        #pragma unroll
        for (int r = 0; r < 4; ++r) {
            gll16(Ag + (long)r * 32 * 1024 + k0, &As[r * 2048 + tid * 8]);
            gll16(Bg + (long)r * 32 * 1024 + k0, &Bs[r * 2048 + tid * 8]);
        }
        __syncthreads();
        #pragma unroll
        for (int kc = 0; kc < 2; ++kc) {
            bf16x8 a[4], b[4];
            #pragma unroll
            for (int i = 0; i < 4; ++i) {
                int R = wr + i * 16 + l15;
                a[i] = *(const bf16x8*)(As + R * 64 + (((kc * 4 + lg) ^ (R & 7)) * 8));
            }
            #pragma unroll
            for (int j = 0; j < 4; ++j) {
                int R = wc + j * 16 + l15;
                b[j] = *(const bf16x8*)(Bs + R * 64 + (((kc * 4 + lg) ^ (R & 7)) * 8));
            }
            #pragma unroll
            for (int i = 0; i < 4; ++i)
                #pragma unroll
                for (int j = 0; j < 4; ++j)
                    acc[i][j] = mfma16(a[i], b[j], acc[i][j]);
        }
    }

    #pragma unroll
    for (int i = 0; i < 4; ++i)
        #pragma unroll
        for (int j = 0; j < 4; ++j)
            #pragma unroll
            for (int r = 0; r < 4; ++r) {
                long row = bm + wr + i * 16 + lg * 4 + r;
                long col = bn + wc + j * 16 + l15;
                C[row * N + col] = (OutT)acc[i][j][r];
            }
}

// ---------------------------------------------------------------------------
__global__ __launch_bounds__(256) void flash_mfma(const __bf16* __restrict__ Qb,
                                                  const __bf16* __restrict__ Kb,
                                                  const __bf16* __restrict__ Vt,
                                                  __bf16* __restrict__ Ob) {
    __shared__ __bf16 Ks[64 * 64];
    __shared__ __bf16 Vs[64 * 64];
    __shared__ __bf16 Ps[64 * 64];
    const int qt = blockIdx.x, h = blockIdx.y, b = blockIdx.z;
    const int tid = threadIdx.x, lane = tid & 63, w = tid >> 6;
    const int l15 = lane & 15, lg = lane >> 4;

    const long qrow = (long)b * SEQ + qt * 64 + w * 16 + l15;
    const bf16x8 qf0 = *(const bf16x8*)(Qb + qrow * DM + h * 64 + lg * 8);
    const bf16x8 qf1 = *(const bf16x8*)(Qb + qrow * DM + h * 64 + 32 + lg * 8);

    f32x4 oacc[4];
    #pragma unroll
    for (int i = 0; i < 4; ++i) oacc[i] = 0;
    float m_run[4], l_run[4];
    #pragma unroll
    for (int r = 0; r < 4; ++r) { m_run[r] = -1e30f; l_run[r] = 0.f; }

    const int srow = tid >> 3;
    const int sgz  = (tid & 7) ^ (srow & 7);
    const __bf16* Kg = Kb + ((long)b * SEQ + srow) * DM + h * 64 + sgz * 8;
    const __bf16* Vg = Vt + ((long)h * 64 + srow) * NTOK + (long)b * SEQ + sgz * 8;

    for (int kt = 0; kt < SEQ / 64; ++kt) {
        __syncthreads();
        gll16(Kg + (long)(kt * 64) * DM,       &Ks[tid * 8]);
        gll16(Kg + (long)(kt * 64 + 32) * DM,  &Ks[2048 + tid * 8]);
        gll16(Vg + kt * 64,                    &Vs[tid * 8]);
        gll16(Vg + (long)32 * NTOK + kt * 64,  &Vs[2048 + tid * 8]);
        __syncthreads();

        f32x4 sc[4];
        #pragma unroll
        for (int j = 0; j < 4; ++j) {
            int R = j * 16 + l15;
            bf16x8 k0v = *(const bf16x8*)(Ks + R * 64 + ((lg       ^ (R & 7)) * 8));
            bf16x8 k1v = *(const bf16x8*)(Ks + R * 64 + (((4 + lg) ^ (R & 7)) * 8));
            f32x4 z = 0;
            z = mfma16(qf0, k0v, z);
            z = mfma16(qf1, k1v, z);
            sc[j] = z * 0.125f;
        }

        float alpha[4];
        #pragma unroll
        for (int r = 0; r < 4; ++r) {
            float mx = fmaxf(fmaxf(sc[0][r], sc[1][r]), fmaxf(sc[2][r], sc[3][r]));
            #pragma unroll
            for (int off = 1; off < 16; off <<= 1) mx = fmaxf(mx, __shfl_xor(mx, off));
            float m_new = fmaxf(m_run[r], mx);
            alpha[r] = __expf(m_run[r] - m_new);
            float rs = 0.f;
            #pragma unroll
            for (int j = 0; j < 4; ++j) {
                float p = __expf(sc[j][r] - m_new);
                sc[j][r] = p;
                rs += p;
            }
            #pragma unroll
            for (int off = 1; off < 16; off <<= 1) rs += __shfl_xor(rs, off);
            l_run[r] = l_run[r] * alpha[r] + rs;
            m_run[r] = m_new;
        }

        #pragma unroll
        for (int r = 0; r < 4; ++r) {
            int q = w * 16 + lg * 4 + r;
            #pragma unroll
            for (int j = 0; j < 4; ++j) {
                int col = j * 16 + l15;
                Ps[q * 64 + (col ^ ((q & 7) << 3))] = (__bf16)sc[j][r];
            }
        }
        __syncthreads();

        {
            int src = (l15 >> 2) * 16;
            float t0 = __shfl(alpha[0], src);
            float t1 = __shfl(alpha[1], src);
            float t2 = __shfl(alpha[2], src);
            float t3 = __shfl(alpha[3], src);
            float am = (l15 & 2) ? ((l15 & 1) ? t3 : t2) : ((l15 & 1) ? t1 : t0);
            #pragma unroll
            for (int i = 0; i < 4; ++i) oacc[i] *= am;
        }

        #pragma unroll
        for (int kc = 0; kc < 2; ++kc) {
            int Rp = w * 16 + l15;
            bf16x8 pb = *(const bf16x8*)(Ps + Rp * 64 + (((kc * 4 + lg) ^ (Rp & 7)) * 8));
            #pragma unroll
            for (int i = 0; i < 4; ++i) {
                int Rv = i * 16 + l15;
                bf16x8 vb = *(const bf16x8*)(Vs + Rv * 64 + (((kc * 4 + lg) ^ (Rv & 7)) * 8));
                oacc[i] = mfma16(vb, pb, oacc[i]);
            }
        }
    }

    int src = (l15 >> 2) * 16;
    float t0 = __shfl(l_run[0], src);
    float t1 = __shfl(l_run[1], src);
    float t2 = __shfl(l_run[2], src);
    float t3 = __shfl(l_run[3], src);
    float lsel = (l15 & 2) ? ((l15 & 1) ? t3 : t2) : ((l15 & 1) ? t1 : t0);
    float linv = 1.0f / lsel;
    const long tok = (long)b * SEQ + qt * 64 + w * 16 + l15;
    #pragma unroll
    for (int i = 0; i < 4; ++i)
        #pragma unroll
        for (int r = 0; r < 4; ++r)
            Ob[tok * DM + h * 64 + i * 16 + lg * 4 + r] = (__bf16)(oacc[i][r] * linv);
}

// ---------------------------------------------------------------------------
extern "C" void kernel_launch(void* const* d_in, const int* in_sizes, int n_in,
                              void* d_out, int out_size, void* d_ws, size_t ws_size,
                              hipStream_t stream) {
    const float* hs = (const float*)d_in[0];
    const float* wq = (const float*)d_in[1];
    const float* wk = (const float*)d_in[2];
    const float* wv = (const float*)d_in[3];
    const float* wo = (const float*)d_in[4];
    float* out = (float*)d_out;

    __bf16* hsb = (__bf16*)d_ws;
    __bf16* wqb = hsb + (long)NTOK * DM;
    __bf16* wkb = wqb + DM * DM;
    __bf16* wvb = wkb + DM * DM;
    __bf16* wob = wvb + DM * DM;
    __bf16* Qb  = wob + DM * DM;
    __bf16* Kb  = Qb + (long)NTOK * DM;
    __bf16* Vtb = Kb + (long)NTOK * DM;
    float*  ct  = (float*)(Vtb + (long)NTOK * DM);
    float*  st  = ct + SEQ * 64;

    rope_tables<<<dim3(SEQ), dim3(64), 0, stream>>>(ct, st);

    f2bf<<<dim3(NTOK * DM / 4 / 256), 256, 0, stream>>>(hs, hsb, NTOK * DM / 4);
    f2bf<<<dim3(DM * DM / 4 / 256), 256, 0, stream>>>(wq, wqb, DM * DM / 4);
    f2bf<<<dim3(DM * DM / 4 / 256), 256, 0, stream>>>(wk, wkb, DM * DM / 4);
    f2bf<<<dim3(DM * DM / 4 / 256), 256, 0, stream>>>(wv, wvb, DM * DM / 4);
    f2bf<<<dim3(DM * DM / 4 / 256), 256, 0, stream>>>(wo, wob, DM * DM / 4);

    gemm_bf16<__bf16><<<dim3(8, 32), 256, 0, stream>>>(hsb, wqb, Qb, 1024);
    gemm_bf16<__bf16><<<dim3(8, 32), 256, 0, stream>>>(hsb, wkb, Kb, 1024);
    gemm_bf16<__bf16><<<dim3(32, 8), 256, 0, stream>>>(wvb, hsb, Vtb, 4096);

    rope_apply_bf16<<<dim3(NTOK * 16 * 32 / 256, 2), 256, 0, stream>>>(Qb, Kb, ct, st);

    flash_mfma<<<dim3(SEQ / 64, 16, 2), 256, 0, stream>>>(Qb, Kb, Vtb, Qb);

    gemm_bf16<float><<<dim3(8, 32), 256, 0, stream>>>(Qb, wob, out, 1024);
}

// Round 3
// 152.186 us; speedup vs baseline: 8.6625x; 1.5053x over previous
//
#include <hip/hip_runtime.h>
#include <math.h>

#define SEQ 2048
#define NTOK 4096
#define DM 1024

typedef __bf16 bf16x8 __attribute__((ext_vector_type(8)));
typedef __bf16 bf16x4 __attribute__((ext_vector_type(4)));
typedef float  f32x4  __attribute__((ext_vector_type(4)));

__device__ __forceinline__ void gll16(const void* g, void* l) {
    __builtin_amdgcn_global_load_lds(
        (const __attribute__((address_space(1))) void*)g,
        (__attribute__((address_space(3))) void*)l, 16, 0, 0);
}

__device__ __forceinline__ f32x4 mfma16(bf16x8 a, bf16x8 b, f32x4 c) {
    return __builtin_amdgcn_mfma_f32_16x16x32_bf16(a, b, c, 0, 0, 0);
}

// ---------------------------------------------------------------------------
__global__ void rope_tables(float* __restrict__ ct, float* __restrict__ st) {
    int s = blockIdx.x;
    int d = threadIdx.x;           // 0..63
    int e = d & 31;
    float invf = 1.0f / powf(10000.0f, (float)e / 32.0f);
    float ang  = (float)s * invf;  // fp32 rounding as in reference
    double a   = (double)ang;
    ct[s * 64 + d] = (float)cos(a);
    st[s * 64 + d] = (float)sin(a);
}

// ---------------------------------------------------------------------------
// merged fp32->bf16 conversion for hs + 4 weights
__global__ void conv_all(const float* __restrict__ hs, const float* __restrict__ wq,
                         const float* __restrict__ wk, const float* __restrict__ wv,
                         const float* __restrict__ wo, __bf16* hsb, __bf16* wqb,
                         __bf16* wkb, __bf16* wvb, __bf16* wob) {
    long i = (long)blockIdx.x * 256 + threadIdx.x;     // 4-element units
    const long H4 = (long)NTOK * DM / 4;               // 1048576
    const float* src; __bf16* dst; long off;
    if (i < H4) { src = hs; dst = hsb; off = i; }
    else {
        long t = i - H4;
        int wsel = (int)(t >> 18);                     // W4 = 262144 = 2^18
        off = t & ((1L << 18) - 1);
        switch (wsel) {
            case 0:  src = wq; dst = wqb; break;
            case 1:  src = wk; dst = wkb; break;
            case 2:  src = wv; dst = wvb; break;
            default: src = wo; dst = wob; break;
        }
    }
    float4 v = ((const float4*)src)[off];
    __bf16* o = dst + off * 4;
    o[0] = (__bf16)v.x; o[1] = (__bf16)v.y; o[2] = (__bf16)v.z; o[3] = (__bf16)v.w;
}

// ---------------------------------------------------------------------------
// C[M,N] = (A[M,K=1024] @ B[N,K]^T) * scale, optional fused RoPE.
// 128x128 tile, BK=64, 4 waves (2x2). global_load_lds(16B), granule-XOR swz.
// ---------------------------------------------------------------------------
template <typename OutT, bool ROPE>
__device__ __forceinline__ void gemm_core(const __bf16* __restrict__ A,
                                          const __bf16* __restrict__ B,
                                          OutT* __restrict__ C, int N, float scale,
                                          const float* __restrict__ ct,
                                          const float* __restrict__ st,
                                          long bm, long bn) {
    __shared__ __bf16 As[128 * 64];
    __shared__ __bf16 Bs[128 * 64];
    const int tid  = threadIdx.x;
    const int lane = tid & 63;
    const int wid  = tid >> 6;
    const int l15  = lane & 15, lg = lane >> 4;
    const int wr = (wid >> 1) * 64, wc = (wid & 1) * 64;

    f32x4 acc[4][4];
    #pragma unroll
    for (int i = 0; i < 4; ++i)
        #pragma unroll
        for (int j = 0; j < 4; ++j) acc[i][j] = 0;

    const int srow = tid >> 3;
    const int sgz  = (tid & 7) ^ (srow & 7);
    const __bf16* Ag = A + (bm + srow) * 1024 + sgz * 8;
    const __bf16* Bg = B + (bn + srow) * 1024 + sgz * 8;

    for (int k0 = 0; k0 < 1024; k0 += 64) {
        __syncthreads();
        #pragma unroll
        for (int r = 0; r < 4; ++r) {
            gll16(Ag + (long)r * 32 * 1024 + k0, &As[r * 2048 + tid * 8]);
            gll16(Bg + (long)r * 32 * 1024 + k0, &Bs[r * 2048 + tid * 8]);
        }
        __syncthreads();
        #pragma unroll
        for (int kc = 0; kc < 2; ++kc) {
            bf16x8 a[4], b[4];
            #pragma unroll
            for (int i = 0; i < 4; ++i) {
                int R = wr + i * 16 + l15;
                a[i] = *(const bf16x8*)(As + R * 64 + (((kc * 4 + lg) ^ (R & 7)) * 8));
            }
            #pragma unroll
            for (int j = 0; j < 4; ++j) {
                int R = wc + j * 16 + l15;
                b[j] = *(const bf16x8*)(Bs + R * 64 + (((kc * 4 + lg) ^ (R & 7)) * 8));
            }
            #pragma unroll
            for (int i = 0; i < 4; ++i)
                #pragma unroll
                for (int j = 0; j < 4; ++j)
                    acc[i][j] = mfma16(a[i], b[j], acc[i][j]);
        }
    }

    if constexpr (ROPE) {
        // cols wc+j*16+l15: head-dim d = j*16+l15 (j<2: d<32, pair at j+2)
        #pragma unroll
        for (int i = 0; i < 4; ++i)
            #pragma unroll
            for (int j = 0; j < 2; ++j)
                #pragma unroll
                for (int r = 0; r < 4; ++r) {
                    long row = bm + wr + i * 16 + lg * 4 + r;
                    int  s   = (int)(row & (SEQ - 1));
                    int  d   = j * 16 + l15;
                    float c  = ct[s * 64 + d];
                    float sn = st[s * 64 + d];
                    float x0 = acc[i][j][r], x1 = acc[i][j + 2][r];
                    long col = bn + wc + j * 16 + l15;
                    C[row * N + col]      = (OutT)((x0 * c - x1 * sn) * scale);
                    C[row * N + col + 32] = (OutT)((x1 * c + x0 * sn) * scale);
                }
    } else {
        #pragma unroll
        for (int i = 0; i < 4; ++i)
            #pragma unroll
            for (int j = 0; j < 4; ++j)
                #pragma unroll
                for (int r = 0; r < 4; ++r) {
                    long row = bm + wr + i * 16 + lg * 4 + r;
                    long col = bn + wc + j * 16 + l15;
                    C[row * N + col] = (OutT)(acc[i][j][r] * scale);
                }
    }
}

template <typename OutT, bool ROPE>
__global__ __launch_bounds__(256) void gemm_k(const __bf16* __restrict__ A,
                                              const __bf16* __restrict__ B,
                                              OutT* __restrict__ C, int N, float scale,
                                              const float* __restrict__ ct,
                                              const float* __restrict__ st) {
    gemm_core<OutT, ROPE>(A, B, C, N, scale, ct, st,
                          (long)blockIdx.y * 128, (long)blockIdx.x * 128);
}

// merged Q+K projection (z selects weight/output/scale); RoPE fused; Q pre-scaled
// by 1/sqrt(hd)=0.125 (exact pow2, lossless in bf16).
__global__ __launch_bounds__(256) void gemm_qk(const __bf16* __restrict__ A,
                                               const __bf16* __restrict__ Bq,
                                               const __bf16* __restrict__ Bk,
                                               __bf16* __restrict__ Cq,
                                               __bf16* __restrict__ Ck,
                                               const float* __restrict__ ct,
                                               const float* __restrict__ st) {
    const __bf16* B = blockIdx.z ? Bk : Bq;
    __bf16* C = blockIdx.z ? Ck : Cq;
    float scale = blockIdx.z ? 1.0f : 0.125f;
    gemm_core<__bf16, true>(A, B, C, 1024, scale, ct, st,
                            (long)blockIdx.y * 128, (long)blockIdx.x * 128);
}

// ---------------------------------------------------------------------------
// Flash attention, swapped QK^T: P[k][q] = mfma(K,Q) puts each q-row's stats on
// lanes sharing l15 -> 2-shfl row reduce, shuffle-free O rescale. Wave-private
// P bounce (no barrier). Double-buffered K/V via global_load_lds: 1 barrier/iter.
// Block = 128 q-rows (4 waves x 32), per (head,batch); O^T accumulated in regs.
// ---------------------------------------------------------------------------
__global__ __launch_bounds__(256) void flash2(const __bf16* __restrict__ Qb,
                                              const __bf16* __restrict__ Kb,
                                              const __bf16* __restrict__ Vt,
                                              __bf16* __restrict__ Ob) {
    __shared__ __bf16 Ks[2][64 * 64];
    __shared__ __bf16 Vs[2][64 * 64];
    __shared__ __bf16 Ps[128 * 64];
    const int qt = blockIdx.x, h = blockIdx.y, b = blockIdx.z;
    const int tid = threadIdx.x, lane = tid & 63, w = tid >> 6;
    const int l15 = lane & 15, lg = lane >> 4;

    // Q B-fragments (2 q-groups x 2 d-chunks), loaded once; Q pre-scaled by 0.125
    bf16x8 qf[2][2];
    #pragma unroll
    for (int qa = 0; qa < 2; ++qa) {
        long qrow = (long)b * SEQ + qt * 128 + w * 32 + qa * 16 + l15;
        qf[qa][0] = *(const bf16x8*)(Qb + qrow * DM + h * 64 + lg * 8);
        qf[qa][1] = *(const bf16x8*)(Qb + qrow * DM + h * 64 + 32 + lg * 8);
    }

    f32x4 oacc[2][4];
    #pragma unroll
    for (int qa = 0; qa < 2; ++qa)
        #pragma unroll
        for (int i = 0; i < 4; ++i) oacc[qa][i] = 0;
    float m_run[2] = {-1e30f, -1e30f}, l_run[2] = {0.f, 0.f};

    const int srow = tid >> 3;                  // 0..31
    const int sgz  = (tid & 7) ^ (srow & 7);    // swizzled source granule
    const __bf16* Kg = Kb + ((long)b * SEQ + srow) * DM + h * 64 + sgz * 8;
    const __bf16* Vg = Vt + ((long)h * 64 + srow) * NTOK + (long)b * SEQ + sgz * 8;

    // stage tile kt into buffer buf (K: [k][d] 64x64; V^T: [d][k] 64x64)
    auto stage = [&](int kt, int buf) {
        gll16(Kg + (long)(kt * 64) * DM,       &Ks[buf][tid * 8]);
        gll16(Kg + (long)(kt * 64 + 32) * DM,  &Ks[buf][2048 + tid * 8]);
        gll16(Vg + kt * 64,                    &Vs[buf][tid * 8]);
        gll16(Vg + (long)32 * NTOK + kt * 64,  &Vs[buf][2048 + tid * 8]);
    };

    stage(0, 0);
    __syncthreads();

    for (int kt = 0; kt < SEQ / 64; ++kt) {
        const int cur = kt & 1;
        if (kt < SEQ / 64 - 1) stage(kt + 1, cur ^ 1);   // prefetch next tile
        const __bf16* Kc = Ks[cur];
        const __bf16* Vc = Vs[cur];

        // QK^T (swapped): sc[qa][j] = P[k = j*16+lg*4+r][q = w*32+qa*16+l15]
        f32x4 sc[2][4];
        #pragma unroll
        for (int j = 0; j < 4; ++j) {
            int R = j * 16 + l15;
            bf16x8 ka0 = *(const bf16x8*)(Kc + R * 64 + ((lg       ^ (R & 7)) * 8));
            bf16x8 ka1 = *(const bf16x8*)(Kc + R * 64 + (((4 + lg) ^ (R & 7)) * 8));
            #pragma unroll
            for (int qa = 0; qa < 2; ++qa) {
                f32x4 z = 0;
                z = mfma16(ka0, qf[qa][0], z);
                z = mfma16(ka1, qf[qa][1], z);
                sc[qa][j] = z;
            }
        }

        // online softmax per q (lane-local + 2 shfl over the 4 lg groups)
        #pragma unroll
        for (int qa = 0; qa < 2; ++qa) {
            float mx = sc[qa][0][0];
            #pragma unroll
            for (int j = 0; j < 4; ++j)
                #pragma unroll
                for (int r = 0; r < 4; ++r) mx = fmaxf(mx, sc[qa][j][r]);
            mx = fmaxf(mx, __shfl_xor(mx, 16));
            mx = fmaxf(mx, __shfl_xor(mx, 32));
            float m_new = fmaxf(m_run[qa], mx);
            float alpha = __expf(m_run[qa] - m_new);
            m_run[qa] = m_new;
            float rs = 0.f;
            #pragma unroll
            for (int j = 0; j < 4; ++j)
                #pragma unroll
                for (int r = 0; r < 4; ++r) {
                    float p = __expf(sc[qa][j][r] - m_new);
                    sc[qa][j][r] = p;
                    rs += p;
                }
            rs += __shfl_xor(rs, 16);
            rs += __shfl_xor(rs, 32);
            l_run[qa] = l_run[qa] * alpha + rs;
            // rescale O^T accum: lane's q-col is l15 -> alpha is already local
            #pragma unroll
            for (int i = 0; i < 4; ++i) oacc[qa][i] *= alpha;
        }

        // P -> LDS (packed b64, swizzled); rows wave-private: no barrier
        #pragma unroll
        for (int qa = 0; qa < 2; ++qa) {
            int q = w * 32 + qa * 16 + l15;
            #pragma unroll
            for (int j = 0; j < 4; ++j) {
                bf16x4 p4;
                p4[0] = (__bf16)sc[qa][j][0];
                p4[1] = (__bf16)sc[qa][j][1];
                p4[2] = (__bf16)sc[qa][j][2];
                p4[3] = (__bf16)sc[qa][j][3];
                int g16 = j * 2 + (lg >> 1);
                *(bf16x4*)(Ps + q * 64 + ((g16 ^ (q & 7)) * 8) + (lg & 1) * 4) = p4;
            }
        }

        // PV: O^T[d][q] += V^T[d][k] * P^T[k][q]
        #pragma unroll
        for (int kc = 0; kc < 2; ++kc) {
            bf16x8 pb[2];
            #pragma unroll
            for (int qa = 0; qa < 2; ++qa) {
                int Rp = w * 32 + qa * 16 + l15;
                pb[qa] = *(const bf16x8*)(Ps + Rp * 64 + (((kc * 4 + lg) ^ (Rp & 7)) * 8));
            }
            #pragma unroll
            for (int i = 0; i < 4; ++i) {
                int Rv = i * 16 + l15;
                bf16x8 vb = *(const bf16x8*)(Vc + Rv * 64 + (((kc * 4 + lg) ^ (Rv & 7)) * 8));
                #pragma unroll
                for (int qa = 0; qa < 2; ++qa)
                    oacc[qa][i] = mfma16(vb, pb[qa], oacc[qa][i]);
            }
        }

        __syncthreads();   // drains vmcnt (prefetch landed) + lgkm; buffers swap
    }

    // epilogue: O[tok][h*64+d] = O^T * (1/l), packed 8B stores
    #pragma unroll
    for (int qa = 0; qa < 2; ++qa) {
        float linv = 1.0f / l_run[qa];
        long tok = (long)b * SEQ + qt * 128 + w * 32 + qa * 16 + l15;
        #pragma unroll
        for (int i = 0; i < 4; ++i) {
            bf16x4 o4;
            #pragma unroll
            for (int r = 0; r < 4; ++r) o4[r] = (__bf16)(oacc[qa][i][r] * linv);
            *(bf16x4*)(Ob + tok * DM + h * 64 + i * 16 + lg * 4) = o4;
        }
    }
}

// ---------------------------------------------------------------------------
extern "C" void kernel_launch(void* const* d_in, const int* in_sizes, int n_in,
                              void* d_out, int out_size, void* d_ws, size_t ws_size,
                              hipStream_t stream) {
    const float* hs = (const float*)d_in[0];
    const float* wq = (const float*)d_in[1];
    const float* wk = (const float*)d_in[2];
    const float* wv = (const float*)d_in[3];
    const float* wo = (const float*)d_in[4];
    float* out = (float*)d_out;

    __bf16* hsb = (__bf16*)d_ws;
    __bf16* wqb = hsb + (long)NTOK * DM;
    __bf16* wkb = wqb + DM * DM;
    __bf16* wvb = wkb + DM * DM;
    __bf16* wob = wvb + DM * DM;
    __bf16* Qb  = wob + DM * DM;                 // attn out aliases Qb (disjoint per block)
    __bf16* Kb  = Qb + (long)NTOK * DM;
    __bf16* Vtb = Kb + (long)NTOK * DM;          // V^T: [1024][4096]
    float*  ct  = (float*)(Vtb + (long)NTOK * DM);
    float*  st  = ct + SEQ * 64;

    rope_tables<<<dim3(SEQ), dim3(64), 0, stream>>>(ct, st);
    conv_all<<<dim3(8192), dim3(256), 0, stream>>>(hs, wq, wk, wv, wo,
                                                   hsb, wqb, wkb, wvb, wob);

    // Q = (hs@wq^T)*0.125 +RoPE ; K = (hs@wk^T) +RoPE   (merged, z=2)
    gemm_qk<<<dim3(8, 32, 2), 256, 0, stream>>>(hsb, wqb, wkb, Qb, Kb, ct, st);
    // V^T = wv @ hs^T  (free transpose via operand swap)
    gemm_k<__bf16, false><<<dim3(32, 8), 256, 0, stream>>>(wvb, hsb, Vtb, 4096, 1.0f,
                                                           nullptr, nullptr);

    flash2<<<dim3(SEQ / 128, 16, 2), 256, 0, stream>>>(Qb, Kb, Vtb, Qb);

    // out = attn @ wo^T (fp32 out)
    gemm_k<float, false><<<dim3(8, 32), 256, 0, stream>>>(Qb, wob, out, 1024, 1.0f,
                                                          nullptr, nullptr);
}